// Round 2
// baseline (225.644 us; speedup 1.0000x reference)
//
#include <hip/hip_runtime.h>

// NCC forces, 192^3 fp32. Round 6 (resubmit after GPU-acquisition timeout):
// LDS-instruction dieting + SIMD balance.
// Model: R5 is LDS-issue-pipe + sync bound (DS ~55-75% issue, VALU 42%,
// nothing saturated). Changes:
//  - T-field: x-phase also writes (m+f) rows into a 4-slot Tf ring; emit's
//    8 scalar gradient reads collapse to 2 read2-mergeable pairs; edge
//    cases use Tc = mc+fc from the register ring (VALU only).
//  - raw ring 5 -> 2 slots (no phase reads old raw slices anymore).
//  - box relayout [pp][x][f][y] (f-stride 20 dwords): emit's 5 box reads
//    merge into 2x ds_read2 + 1; y-phase write stays 2x b128.
//  - ZSEG 12 -> 16: halo amortization 17/12 -> 21/16 (-7.4% phase work).
//  - per-SIMD role rotation by (b>>8)&3: x/y-phase waves of co-resident
//    blocks land on different SIMDs (wave->SIMD is round-robin).
//  - mask loads prefetched one full iteration ahead.
// LDS 34880 B -> 4 blocks/CU (unchanged). Bank patterns audited <=2-way.

#define DD 192
#define HH 192
#define WW 192
#define NVOX (DD * HH * WW)
#define SLICE (HH * WW)
#define TS 16
#define RR 20            // staged rows (y: y0-2 .. y0+17)
#define RW 24            // staged row width (x: x0-4 .. x0+19)
#define ZSEG 16
#define NBX 12
#define NBY 12
#define NBZ 12
#define NBLK (NBX * NBY * NBZ)        // 1728
#define PER_XCD (NBLK / 8)            // 216

__global__ __launch_bounds__(256)
void ncc_forces_kernel(const float* __restrict__ mimg,
                       const float* __restrict__ fimg,
                       const int*   __restrict__ mmask,
                       const int*   __restrict__ fmask,
                       float* __restrict__ out)
{
    __shared__ float rawm[2][RR][RW];     // 3840 B
    __shared__ float rawf[2][RR][RW];     // 3840 B
    __shared__ float xs[5][RR][20];       // 8000 B  [field][yrow][xo]
    __shared__ float Tf[4][RR][20];       // 6400 B  (m+f); col k <-> raw local k+2
    __shared__ float box[2][TS][5][20];   // 12800 B [pp][x][field][yout]

    // XCD swizzle: XCD k gets 216 consecutive logical blocks
    const int b  = blockIdx.x;
    const int L  = (b & 7) * PER_XCD + (b >> 3);
    const int bz = L / (NBX * NBY);
    const int r_ = L - bz * (NBX * NBY);
    const int by = r_ / NBX;
    const int bx = r_ - by * NBX;

    const int tid  = threadIdx.x;
    const int rtid = (tid + (((b >> 8) & 3) << 6)) & 255;   // role rotation
    const int tx = tid & 15, ty = tid >> 4;
    const int x0 = bx * TS, y0 = by * TS, z0 = bz * ZSEG;

    // ---- staging roles (rtid-based): 240 lanes = 2 images x 20 rows x 6 quads
    const int  simg   = rtid / 120;           // 0,1 stager; 2 idle
    const bool stager = (simg < 2);
    const int  st     = rtid - simg * 120;
    const int  srow   = st / 6;
    const int  squad  = st - srow * 6;
    const int  sgy    = y0 - 2 + srow;
    const int  sgx    = x0 - 4 + 4 * squad;   // quads all-in or all-out
    const bool sin_   = (sgy >= 0) && (sgy < HH) && (sgx >= 0) && (sgx <= WW - 4);
    const float* sptr = (simg == 1) ? fimg : mimg;
    float* sldsb = (simg == 1) ? &rawf[0][0][0] : &rawm[0][0][0];
    const int  sloff  = srow * RW + 4 * squad;

    float4 pref = make_float4(0, 0, 0, 0);
    auto prefetch = [&](int zz) {
        pref = make_float4(0, 0, 0, 0);
        if (stager && sin_ && zz >= 0 && zz < DD)
            pref = *(const float4*)(sptr + ((size_t)zz * HH + sgy) * WW + sgx);
    };

    // per-thread rings
    float ring[5][5];
#pragma unroll
    for (int s = 0; s < 5; ++s)
#pragma unroll
        for (int f = 0; f < 5; ++f) ring[s][f] = 0.f;
    float cm[5] = {0, 0, 0, 0, 0}, cf[5] = {0, 0, 0, 0, 0};

    const int gx = x0 + tx, gy = y0 + ty;
    const int vbase = (z0 * HH + gy) * WW + gx;   // voxel index at z=z0
    int umN = 0, ufN = 0;                          // masks prefetched 1 iter ahead

    prefetch(z0 - 2);

    for (int n = 0; n <= ZSEG + 4; ++n) {
        const int zc = z0 - 2 + n;           // slice committed this iter
        const int sw = n & 1;                // raw slot (write+read same iter)
        const int z  = zc - 3;               // slice emitted this iter
        const bool emitv = (n >= 5);

        // ---- commit staged slice zc; issue loads for zc+1 ----
        if (stager) *(float4*)(sldsb + sw * (RR * RW) + sloff) = pref;
        prefetch(zc + 1);

        const int um = umN, uf = ufN;        // masks for THIS iter's emit
        if (n >= 4 && n < ZSEG + 4) {        // prefetch for iter n+1
            const int vn = vbase + (n - 4) * SLICE;
            umN = __builtin_nontemporal_load(mmask + vn);
            ufN = __builtin_nontemporal_load(fmask + vn);
        }

        __syncthreads();   // A: raw[sw] ready; box[(n-1)&1] ready

        // ---- x-phase: 80 chunk-of-4 tasks; also emits T = m+f row ----
        if (rtid < 80) {
            const int yy = rtid >> 2;          // 0..19
            const int t4 = (rtid & 3) * 4;     // 0,4,8,12
            const float4 A0 = *(const float4*)&rawm[sw][yy][t4];
            const float4 A1 = *(const float4*)&rawm[sw][yy][t4 + 4];
            const float2 A2 = *(const float2*)&rawm[sw][yy][t4 + 8];
            const float4 B0 = *(const float4*)&rawf[sw][yy][t4];
            const float4 B1 = *(const float4*)&rawf[sw][yy][t4 + 4];
            const float2 B2 = *(const float2*)&rawf[sw][yy][t4 + 8];
            const float a[10]  = {A0.x, A0.y, A0.z, A0.w, A1.x, A1.y, A1.z, A1.w, A2.x, A2.y};
            const float bb[10] = {B0.x, B0.y, B0.z, B0.w, B1.x, B1.y, B1.z, B1.w, B2.x, B2.y};
            float p[10], s, w0, w1, w2, w3;
#pragma unroll
            for (int f = 0; f < 5; ++f) {
#pragma unroll
                for (int i = 2; i < 10; ++i) {
                    p[i] = (f == 0) ? a[i] : (f == 1) ? bb[i] :
                           (f == 2) ? a[i] * a[i] : (f == 3) ? bb[i] * bb[i] : a[i] * bb[i];
                }
                s = p[2] + p[3] + p[4] + p[5] + p[6]; w0 = s;
                s += p[7] - p[2]; w1 = s;
                s += p[8] - p[3]; w2 = s;
                s += p[9] - p[4]; w3 = s;
                *(float4*)&xs[f][yy][t4] = make_float4(w0, w1, w2, w3);
            }
            // T[yy][k] = (m+f) at raw local k+2  (k = 0..19)
            const int tw = n & 3;
            *(float4*)&Tf[tw][yy][t4] =
                make_float4(a[2] + bb[2], a[3] + bb[3], a[4] + bb[4], a[5] + bb[5]);
            if (t4 == 12)
                *(float4*)&Tf[tw][yy][16] =
                    make_float4(a[6] + bb[6], a[7] + bb[7], a[8] + bb[8], a[9] + bb[9]);
        }

        // ---- centers: fresh slice zc -> register ring ----
        {
            const float ncm = rawm[sw][ty + 2][tx + 4];
            const float ncf = rawf[sw][ty + 2][tx + 4];
#pragma unroll
            for (int s2 = 4; s2 > 0; --s2) { cm[s2] = cm[s2 - 1]; cf[s2] = cf[s2 - 1]; }
            cm[0] = ncm; cf[0] = ncf;
        }
        // 2D sums of slice zc-1 (y-phase of iter n-1) -> ring
        if (n >= 1) {
            const int pp = (n - 1) & 1;
            const float* bq = &box[pp][tx][0][ty];    // f-stride 20 dwords -> read2 merge
            const float s0 = bq[0], s1 = bq[20], s2v = bq[40], s3 = bq[60], s4 = bq[80];
#pragma unroll
            for (int s = 0; s < 4; ++s)
#pragma unroll
                for (int f = 0; f < 5; ++f) ring[s][f] = ring[s + 1][f];
            ring[4][0] = s0; ring[4][1] = s1; ring[4][2] = s2v; ring[4][3] = s3; ring[4][4] = s4;
        }

        if (emitv) {
            float sum_m = 0.f, sum_f = 0.f, sum_mm = 0.f, sum_ff = 0.f, sum_mf = 0.f;
#pragma unroll
            for (int s = 0; s < 5; ++s) {
                sum_m  += ring[s][0];
                sum_f  += ring[s][1];
                sum_mm += ring[s][2];
                sum_ff += ring[s][3];
                sum_mf += ring[s][4];
            }
            const int vidx = vbase + (n - 5) * SLICE;
            const int tsl = (n + 1) & 3;       // T slot of slice z (written iter n-3)
            const int cy = ty + 2;
            const float mc = cm[3];            // center at z
            const float fc = cf[3];
            const float Tc = mc + fc;

            // gradient sums via T field: 2 read2-mergeable pairs
            const float* tp = &Tf[tsl][cy][tx + 1];       // {gx-1, gx+1}: offs 0,2
            const float Txm = tp[0], Txp = tp[2];
            const float* tq = &Tf[tsl][cy - 1][tx + 2];   // {gy-1, gy+1}: offs 0,40
            const float Tym = tq[0], Typ = tq[40];

            float gsx, gsy, gsz;
            if (gx == 0)          gsx = Txp - Tc;
            else if (gx == WW-1)  gsx = Tc - Txm;
            else                  gsx = 0.5f * (Txp - Txm);
            if (gy == 0)          gsy = Typ - Tc;
            else if (gy == HH-1)  gsy = Tc - Tym;
            else                  gsy = 0.5f * (Typ - Tym);
            const float Tzm = cm[4] + cf[4], Tzp = cm[2] + cf[2];
            if (z == 0)           gsz = Tzp - Tc;
            else if (z == DD-1)   gsz = Tc - Tzm;
            else                  gsz = 0.5f * (Tzp - Tzm);

            const float u = ((um != 0) || (uf != 0)) ? 1.0f : 0.0f;

            const float npix = 125.0f;
            const float inv_npix = 1.0f / 125.0f;
            const float mean_m = sum_m * inv_npix;
            const float mean_f = sum_f * inv_npix;
            const float var_m = sum_mm - 2.0f * mean_m * sum_m + npix * mean_m * mean_m;
            const float var_f = sum_ff - 2.0f * mean_f * sum_f + npix * mean_f * mean_f;
            const float var_mf = var_m * var_f;
            const float cross = sum_mf - mean_f * sum_m - mean_m * sum_f + npix * mean_m * mean_f;
            const float mmc = mc - mean_m;
            const float fmc = fc - mean_f;
            const bool ok = (var_mf > 1e-5f) && (var_f > 1e-5f) && (fmc != 0.0f) && (mmc != 0.0f);
            float factor = 0.0f;
            if (ok) factor = 2.0f * cross / var_mf * (mmc - cross * fmc / var_f);

            const float nf = -factor * 0.5f * u;
            out[vidx]            = nf * gsz;   // ch 0: d/dD
            out[NVOX + vidx]     = nf * gsy;   // ch 1: d/dH
            out[2 * NVOX + vidx] = nf * gsx;   // ch 2: d/dW
        }

        __syncthreads();   // B: xs/Tf ready; emit reads of box done

        // ---- y-phase: 160 chunk-of-8 sliding tasks -> box[n&1] ----
        if (rtid < 160) {
            const int x  = rtid & 15;
            const int c8 = ((rtid >> 4) & 1) * 8;  // 0 or 8
            const int f  = rtid >> 5;              // 0..4
            const float* xp = &xs[f][c8][x];       // stride 20 dwords -> read2 merge
            float v[12];
#pragma unroll
            for (int j = 0; j < 12; ++j) v[j] = xp[20 * j];
            float o[8];
            float s = v[0] + v[1] + v[2] + v[3] + v[4];
            o[0] = s;
#pragma unroll
            for (int j = 1; j < 8; ++j) { s += v[j + 4] - v[j - 1]; o[j] = s; }
            float* bp = &box[n & 1][x][f][c8];
            *(float4*)bp       = make_float4(o[0], o[1], o[2], o[3]);
            *(float4*)(bp + 4) = make_float4(o[4], o[5], o[6], o[7]);
        }
        // no trailing barrier:
        //  - next commit writes raw[(n+1)&1]; this iter read raw[n&1] only.
        //  - next x-phase (writes xs/Tf[(n+1)&3]) is fenced by next barrier A;
        //    Tf[(n+1)&3] was last read at emit(n) before B(n).
        //  - box[n&1] is read at emit(n+1) after A(n+1), rewritten at y(n+2).
    }
}

extern "C" void kernel_launch(void* const* d_in, const int* in_sizes, int n_in,
                              void* d_out, int out_size, void* d_ws, size_t ws_size,
                              hipStream_t stream)
{
    const float* mimg  = (const float*)d_in[0];
    const float* fimg  = (const float*)d_in[1];
    const int*   mmask = (const int*)d_in[2];
    const int*   fmask = (const int*)d_in[3];
    float* out = (float*)d_out;

    dim3 grid(NBLK, 1, 1);   // 1728 blocks
    dim3 block(256, 1, 1);
    hipLaunchKernelGGL(ncc_forces_kernel, grid, block, 0, stream,
                       mimg, fimg, mmask, fmask, out);
}

// Round 3
// 211.210 us; speedup vs baseline: 1.0683x; 1.0683x over previous
//
#include <hip/hip_runtime.h>

// NCC forces, 192^3 fp32. Round 7: R5 skeleton + LDS diet only.
// R6 post-mortem: +23% duration with ALL event counters flat per unit work
// and VALUBusy% unchanged -> session-rate confound suspected, but ZSEG-16
// and role rotation could not be exonerated. This round reverts to the
// proven R5 grid (ZSEG 12, 2304 blocks = exactly 9/CU, tid roles) and keeps
// only the DS-instruction diet:
//  - T-field: x-phase also writes (m+f) rows into a 4-slot Tf ring; emit's
//    8 scalar gradient reads -> 2 read2-mergeable pairs; edges use
//    Tc = mc+fc from the register ring (VALU only).
//  - raw ring 5 -> 2 slots (no phase reads old raw slices anymore).
//  - box relayout [pp][x][f][y] (f-stride 20 dwords): emit's 5 box reads
//    merge into 2x ds_read2 + 1; y-phase write stays 2x b128.
//  - mask loads prefetched one full iteration ahead.
// LDS 34880 B -> 4 blocks/CU. Bank patterns audited <=2-way (box read:
// 4tx+ty covers each bank exactly 2x per wave).

#define DD 192
#define HH 192
#define WW 192
#define NVOX (DD * HH * WW)
#define SLICE (HH * WW)
#define TS 16
#define RR 20            // staged rows (y: y0-2 .. y0+17)
#define RW 24            // staged row width (x: x0-4 .. x0+19)
#define ZSEG 12
#define NBX 12
#define NBY 12
#define NBZ 16
#define NBLK (NBX * NBY * NBZ)        // 2304
#define PER_XCD (NBLK / 8)            // 288

__global__ __launch_bounds__(256)
void ncc_forces_kernel(const float* __restrict__ mimg,
                       const float* __restrict__ fimg,
                       const int*   __restrict__ mmask,
                       const int*   __restrict__ fmask,
                       float* __restrict__ out)
{
    __shared__ float rawm[2][RR][RW];     // 3840 B
    __shared__ float rawf[2][RR][RW];     // 3840 B
    __shared__ float xs[5][RR][20];       // 8000 B  [field][yrow][xo]
    __shared__ float Tf[4][RR][20];       // 6400 B  (m+f); col k <-> raw local k+2
    __shared__ float box[2][TS][5][20];   // 12800 B [pp][x][field][yout]

    // XCD swizzle: XCD k gets 288 consecutive logical blocks (2 z-slabs)
    const int b  = blockIdx.x;
    const int L  = (b & 7) * PER_XCD + (b >> 3);
    const int bz = L / (NBX * NBY);
    const int r_ = L - bz * (NBX * NBY);
    const int by = r_ / NBX;
    const int bx = r_ - by * NBX;

    const int tid = threadIdx.x;
    const int tx = tid & 15, ty = tid >> 4;
    const int x0 = bx * TS, y0 = by * TS, z0 = bz * ZSEG;

    // ---- staging roles: 240 lanes = 2 images x 20 rows x 6 quads ----
    const int  simg   = tid / 120;            // 0,1 stager; 2 idle
    const bool stager = (simg < 2);
    const int  st     = tid - simg * 120;
    const int  srow   = st / 6;
    const int  squad  = st - srow * 6;
    const int  sgy    = y0 - 2 + srow;
    const int  sgx    = x0 - 4 + 4 * squad;   // quads all-in or all-out (x0%16==0)
    const bool sin_   = (sgy >= 0) && (sgy < HH) && (sgx >= 0) && (sgx <= WW - 4);
    const float* sptr = (simg == 1) ? fimg : mimg;
    float* sldsb = (simg == 1) ? &rawf[0][0][0] : &rawm[0][0][0];
    const int  sloff  = srow * RW + 4 * squad;

    float4 pref = make_float4(0, 0, 0, 0);
    auto prefetch = [&](int zz) {
        pref = make_float4(0, 0, 0, 0);
        if (stager && sin_ && zz >= 0 && zz < DD)
            pref = *(const float4*)(sptr + ((size_t)zz * HH + sgy) * WW + sgx);
    };

    // per-thread rings
    float ring[5][5];
#pragma unroll
    for (int s = 0; s < 5; ++s)
#pragma unroll
        for (int f = 0; f < 5; ++f) ring[s][f] = 0.f;
    float cm[5] = {0, 0, 0, 0, 0}, cf[5] = {0, 0, 0, 0, 0};

    const int gx = x0 + tx, gy = y0 + ty;
    const int vbase = (z0 * HH + gy) * WW + gx;   // voxel index at z=z0
    int umN = 0, ufN = 0;                          // masks prefetched 1 iter ahead

    prefetch(z0 - 2);

    for (int n = 0; n <= ZSEG + 4; ++n) {
        const int zc = z0 - 2 + n;           // slice committed this iter
        const int sw = n & 1;                // raw slot (write+read same iter)
        const int z  = zc - 3;               // slice emitted this iter
        const bool emitv = (n >= 5);

        // ---- commit staged slice zc; issue loads for zc+1 ----
        if (stager) *(float4*)(sldsb + sw * (RR * RW) + sloff) = pref;
        prefetch(zc + 1);

        const int um = umN, uf = ufN;        // masks for THIS iter's emit
        if (n >= 4 && n < ZSEG + 4) {        // prefetch for iter n+1
            const int vn = vbase + (n - 4) * SLICE;
            umN = __builtin_nontemporal_load(mmask + vn);
            ufN = __builtin_nontemporal_load(fmask + vn);
        }

        __syncthreads();   // A: raw[sw] ready; box[(n-1)&1] ready

        // ---- x-phase: 80 chunk-of-4 tasks; also emits T = m+f row ----
        if (tid < 80) {
            const int yy = tid >> 2;          // 0..19
            const int t4 = (tid & 3) * 4;     // 0,4,8,12
            const float4 A0 = *(const float4*)&rawm[sw][yy][t4];
            const float4 A1 = *(const float4*)&rawm[sw][yy][t4 + 4];
            const float2 A2 = *(const float2*)&rawm[sw][yy][t4 + 8];
            const float4 B0 = *(const float4*)&rawf[sw][yy][t4];
            const float4 B1 = *(const float4*)&rawf[sw][yy][t4 + 4];
            const float2 B2 = *(const float2*)&rawf[sw][yy][t4 + 8];
            const float a[10]  = {A0.x, A0.y, A0.z, A0.w, A1.x, A1.y, A1.z, A1.w, A2.x, A2.y};
            const float bb[10] = {B0.x, B0.y, B0.z, B0.w, B1.x, B1.y, B1.z, B1.w, B2.x, B2.y};
            float p[10], s, w0, w1, w2, w3;
#pragma unroll
            for (int f = 0; f < 5; ++f) {
#pragma unroll
                for (int i = 2; i < 10; ++i) {
                    p[i] = (f == 0) ? a[i] : (f == 1) ? bb[i] :
                           (f == 2) ? a[i] * a[i] : (f == 3) ? bb[i] * bb[i] : a[i] * bb[i];
                }
                s = p[2] + p[3] + p[4] + p[5] + p[6]; w0 = s;
                s += p[7] - p[2]; w1 = s;
                s += p[8] - p[3]; w2 = s;
                s += p[9] - p[4]; w3 = s;
                *(float4*)&xs[f][yy][t4] = make_float4(w0, w1, w2, w3);
            }
            // T[yy][k] = (m+f) at raw local k+2  (k = 0..19)
            const int tw = n & 3;
            *(float4*)&Tf[tw][yy][t4] =
                make_float4(a[2] + bb[2], a[3] + bb[3], a[4] + bb[4], a[5] + bb[5]);
            if (t4 == 12)
                *(float4*)&Tf[tw][yy][16] =
                    make_float4(a[6] + bb[6], a[7] + bb[7], a[8] + bb[8], a[9] + bb[9]);
        }

        // ---- centers: fresh slice zc -> register ring ----
        {
            const float ncm = rawm[sw][ty + 2][tx + 4];
            const float ncf = rawf[sw][ty + 2][tx + 4];
#pragma unroll
            for (int s2 = 4; s2 > 0; --s2) { cm[s2] = cm[s2 - 1]; cf[s2] = cf[s2 - 1]; }
            cm[0] = ncm; cf[0] = ncf;
        }
        // 2D sums of slice zc-1 (y-phase of iter n-1) -> ring
        if (n >= 1) {
            const int pp = (n - 1) & 1;
            const float* bq = &box[pp][tx][0][ty];    // f-stride 20 dwords -> read2 merge
            const float s0 = bq[0], s1 = bq[20], s2v = bq[40], s3 = bq[60], s4 = bq[80];
#pragma unroll
            for (int s = 0; s < 4; ++s)
#pragma unroll
                for (int f = 0; f < 5; ++f) ring[s][f] = ring[s + 1][f];
            ring[4][0] = s0; ring[4][1] = s1; ring[4][2] = s2v; ring[4][3] = s3; ring[4][4] = s4;
        }

        if (emitv) {
            float sum_m = 0.f, sum_f = 0.f, sum_mm = 0.f, sum_ff = 0.f, sum_mf = 0.f;
#pragma unroll
            for (int s = 0; s < 5; ++s) {
                sum_m  += ring[s][0];
                sum_f  += ring[s][1];
                sum_mm += ring[s][2];
                sum_ff += ring[s][3];
                sum_mf += ring[s][4];
            }
            const int vidx = vbase + (n - 5) * SLICE;
            const int tsl = (n + 1) & 3;       // T slot of slice z (written iter n-3)
            const int cy = ty + 2;
            const float mc = cm[3];            // center at z
            const float fc = cf[3];
            const float Tc = mc + fc;

            // gradient sums via T field: 2 read2-mergeable pairs
            const float* tp = &Tf[tsl][cy][tx + 1];       // {gx-1, gx+1}: offs 0,2
            const float Txm = tp[0], Txp = tp[2];
            const float* tq = &Tf[tsl][cy - 1][tx + 2];   // {gy-1, gy+1}: offs 0,40
            const float Tym = tq[0], Typ = tq[40];

            float gsx, gsy, gsz;
            if (gx == 0)          gsx = Txp - Tc;
            else if (gx == WW-1)  gsx = Tc - Txm;
            else                  gsx = 0.5f * (Txp - Txm);
            if (gy == 0)          gsy = Typ - Tc;
            else if (gy == HH-1)  gsy = Tc - Tym;
            else                  gsy = 0.5f * (Typ - Tym);
            const float Tzm = cm[4] + cf[4], Tzp = cm[2] + cf[2];
            if (z == 0)           gsz = Tzp - Tc;
            else if (z == DD-1)   gsz = Tc - Tzm;
            else                  gsz = 0.5f * (Tzp - Tzm);

            const float u = ((um != 0) || (uf != 0)) ? 1.0f : 0.0f;

            const float npix = 125.0f;
            const float inv_npix = 1.0f / 125.0f;
            const float mean_m = sum_m * inv_npix;
            const float mean_f = sum_f * inv_npix;
            const float var_m = sum_mm - 2.0f * mean_m * sum_m + npix * mean_m * mean_m;
            const float var_f = sum_ff - 2.0f * mean_f * sum_f + npix * mean_f * mean_f;
            const float var_mf = var_m * var_f;
            const float cross = sum_mf - mean_f * sum_m - mean_m * sum_f + npix * mean_m * mean_f;
            const float mmc = mc - mean_m;
            const float fmc = fc - mean_f;
            const bool ok = (var_mf > 1e-5f) && (var_f > 1e-5f) && (fmc != 0.0f) && (mmc != 0.0f);
            float factor = 0.0f;
            if (ok) factor = 2.0f * cross / var_mf * (mmc - cross * fmc / var_f);

            const float nf = -factor * 0.5f * u;
            out[vidx]            = nf * gsz;   // ch 0: d/dD
            out[NVOX + vidx]     = nf * gsy;   // ch 1: d/dH
            out[2 * NVOX + vidx] = nf * gsx;   // ch 2: d/dW
        }

        __syncthreads();   // B: xs/Tf ready; emit reads of box done

        // ---- y-phase: 160 chunk-of-8 sliding tasks -> box[n&1] ----
        if (tid < 160) {
            const int x  = tid & 15;
            const int c8 = ((tid >> 4) & 1) * 8;   // 0 or 8
            const int f  = tid >> 5;               // 0..4
            const float* xp = &xs[f][c8][x];       // stride 20 dwords -> read2 merge
            float v[12];
#pragma unroll
            for (int j = 0; j < 12; ++j) v[j] = xp[20 * j];
            float o[8];
            float s = v[0] + v[1] + v[2] + v[3] + v[4];
            o[0] = s;
#pragma unroll
            for (int j = 1; j < 8; ++j) { s += v[j + 4] - v[j - 1]; o[j] = s; }
            float* bp = &box[n & 1][x][f][c8];
            *(float4*)bp       = make_float4(o[0], o[1], o[2], o[3]);
            *(float4*)(bp + 4) = make_float4(o[4], o[5], o[6], o[7]);
        }
        // no trailing barrier:
        //  - next commit writes raw[(n+1)&1]; this iter read raw[n&1] only.
        //  - next x-phase (writes xs/Tf[(n+1)&3]) is fenced by next barrier A;
        //    Tf[(n+1)&3] was last read at emit(n) before B(n).
        //  - box[n&1] is read at emit(n+1) after A(n+1), rewritten at y(n+2).
    }
}

extern "C" void kernel_launch(void* const* d_in, const int* in_sizes, int n_in,
                              void* d_out, int out_size, void* d_ws, size_t ws_size,
                              hipStream_t stream)
{
    const float* mimg  = (const float*)d_in[0];
    const float* fimg  = (const float*)d_in[1];
    const int*   mmask = (const int*)d_in[2];
    const int*   fmask = (const int*)d_in[3];
    float* out = (float*)d_out;

    dim3 grid(NBLK, 1, 1);   // 2304 blocks
    dim3 block(256, 1, 1);
    hipLaunchKernelGGL(ncc_forces_kernel, grid, block, 0, stream,
                       mimg, fimg, mmask, fmask, out);
}

// Round 4
// 210.292 us; speedup vs baseline: 1.0730x; 1.0044x over previous
//
#include <hip/hip_runtime.h>

// NCC forces, 192^3 fp32. Round 8: single-slot raw -> 5 blocks/CU.
// R7 post-mortem: LDS diet was time-neutral (84.4 vs 83.7 us) -> kernel is
// NOT LDS-issue-bound. VALU 42%, HBM 23%, conflicts 233cyc/iter: model is
// latency/sync-bound at 2.75 co-resident blocks (cap 4 by LDS).
// Change: raw double-buffer is vestigial (written at commit, read only in
// [A,B]; barrier B separates iter-n reads from commit(n+1) writes). Single
// slot saves 3840 B: LDS 34880 -> 31040 (-> 31232 alloc) -> 5 blocks/CU,
// occupancy cap 50% -> 62.5%. No arithmetic change.

#define DD 192
#define HH 192
#define WW 192
#define NVOX (DD * HH * WW)
#define SLICE (HH * WW)
#define TS 16
#define RR 20            // staged rows (y: y0-2 .. y0+17)
#define RW 24            // staged row width (x: x0-4 .. x0+19)
#define ZSEG 12
#define NBX 12
#define NBY 12
#define NBZ 16
#define NBLK (NBX * NBY * NBZ)        // 2304
#define PER_XCD (NBLK / 8)            // 288

__global__ __launch_bounds__(256)
void ncc_forces_kernel(const float* __restrict__ mimg,
                       const float* __restrict__ fimg,
                       const int*   __restrict__ mmask,
                       const int*   __restrict__ fmask,
                       float* __restrict__ out)
{
    __shared__ float rawm[RR][RW];        // 1920 B (single slot)
    __shared__ float rawf[RR][RW];        // 1920 B
    __shared__ float xs[5][RR][20];       // 8000 B  [field][yrow][xo]
    __shared__ float Tf[4][RR][20];       // 6400 B  (m+f); col k <-> raw local k+2
    __shared__ float box[2][TS][5][20];   // 12800 B [pp][x][field][yout]
    // total 31040 B -> 5 blocks/CU

    // XCD swizzle: XCD k gets 288 consecutive logical blocks (2 z-slabs)
    const int b  = blockIdx.x;
    const int L  = (b & 7) * PER_XCD + (b >> 3);
    const int bz = L / (NBX * NBY);
    const int r_ = L - bz * (NBX * NBY);
    const int by = r_ / NBX;
    const int bx = r_ - by * NBX;

    const int tid = threadIdx.x;
    const int tx = tid & 15, ty = tid >> 4;
    const int x0 = bx * TS, y0 = by * TS, z0 = bz * ZSEG;

    // ---- staging roles: 240 lanes = 2 images x 20 rows x 6 quads ----
    const int  simg   = tid / 120;            // 0,1 stager; 2 idle
    const bool stager = (simg < 2);
    const int  st     = tid - simg * 120;
    const int  srow   = st / 6;
    const int  squad  = st - srow * 6;
    const int  sgy    = y0 - 2 + srow;
    const int  sgx    = x0 - 4 + 4 * squad;   // quads all-in or all-out (x0%16==0)
    const bool sin_   = (sgy >= 0) && (sgy < HH) && (sgx >= 0) && (sgx <= WW - 4);
    const float* sptr = (simg == 1) ? fimg : mimg;
    float* sldsb = (simg == 1) ? &rawf[0][0] : &rawm[0][0];
    const int  sloff  = srow * RW + 4 * squad;

    float4 pref = make_float4(0, 0, 0, 0);
    auto prefetch = [&](int zz) {
        pref = make_float4(0, 0, 0, 0);
        if (stager && sin_ && zz >= 0 && zz < DD)
            pref = *(const float4*)(sptr + ((size_t)zz * HH + sgy) * WW + sgx);
    };

    // per-thread rings
    float ring[5][5];
#pragma unroll
    for (int s = 0; s < 5; ++s)
#pragma unroll
        for (int f = 0; f < 5; ++f) ring[s][f] = 0.f;
    float cm[5] = {0, 0, 0, 0, 0}, cf[5] = {0, 0, 0, 0, 0};

    const int gx = x0 + tx, gy = y0 + ty;
    const int vbase = (z0 * HH + gy) * WW + gx;   // voxel index at z=z0
    int umN = 0, ufN = 0;                          // masks prefetched 1 iter ahead

    prefetch(z0 - 2);

    for (int n = 0; n <= ZSEG + 4; ++n) {
        const int zc = z0 - 2 + n;           // slice committed this iter
        const int z  = zc - 3;               // slice emitted this iter
        const bool emitv = (n >= 5);

        // ---- commit staged slice zc; issue loads for zc+1 ----
        // WAR vs iter-(n-1)'s raw reads is fenced by barrier B of iter n-1.
        if (stager) *(float4*)(sldsb + sloff) = pref;
        prefetch(zc + 1);

        const int um = umN, uf = ufN;        // masks for THIS iter's emit
        if (n >= 4 && n < ZSEG + 4) {        // prefetch for iter n+1
            const int vn = vbase + (n - 4) * SLICE;
            umN = __builtin_nontemporal_load(mmask + vn);
            ufN = __builtin_nontemporal_load(fmask + vn);
        }

        __syncthreads();   // A: raw ready; box[(n-1)&1] (y of n-1) ready

        // ---- x-phase: 80 chunk-of-4 tasks; also emits T = m+f row ----
        if (tid < 80) {
            const int yy = tid >> 2;          // 0..19
            const int t4 = (tid & 3) * 4;     // 0,4,8,12
            const float4 A0 = *(const float4*)&rawm[yy][t4];
            const float4 A1 = *(const float4*)&rawm[yy][t4 + 4];
            const float2 A2 = *(const float2*)&rawm[yy][t4 + 8];
            const float4 B0 = *(const float4*)&rawf[yy][t4];
            const float4 B1 = *(const float4*)&rawf[yy][t4 + 4];
            const float2 B2 = *(const float2*)&rawf[yy][t4 + 8];
            const float a[10]  = {A0.x, A0.y, A0.z, A0.w, A1.x, A1.y, A1.z, A1.w, A2.x, A2.y};
            const float bb[10] = {B0.x, B0.y, B0.z, B0.w, B1.x, B1.y, B1.z, B1.w, B2.x, B2.y};
            float p[10], s, w0, w1, w2, w3;
#pragma unroll
            for (int f = 0; f < 5; ++f) {
#pragma unroll
                for (int i = 2; i < 10; ++i) {
                    p[i] = (f == 0) ? a[i] : (f == 1) ? bb[i] :
                           (f == 2) ? a[i] * a[i] : (f == 3) ? bb[i] * bb[i] : a[i] * bb[i];
                }
                s = p[2] + p[3] + p[4] + p[5] + p[6]; w0 = s;
                s += p[7] - p[2]; w1 = s;
                s += p[8] - p[3]; w2 = s;
                s += p[9] - p[4]; w3 = s;
                *(float4*)&xs[f][yy][t4] = make_float4(w0, w1, w2, w3);
            }
            // T[yy][k] = (m+f) at raw local k+2  (k = 0..19)
            const int tw = n & 3;
            *(float4*)&Tf[tw][yy][t4] =
                make_float4(a[2] + bb[2], a[3] + bb[3], a[4] + bb[4], a[5] + bb[5]);
            if (t4 == 12)
                *(float4*)&Tf[tw][yy][16] =
                    make_float4(a[6] + bb[6], a[7] + bb[7], a[8] + bb[8], a[9] + bb[9]);
        }

        // ---- centers: fresh slice zc -> register ring ----
        {
            const float ncm = rawm[ty + 2][tx + 4];
            const float ncf = rawf[ty + 2][tx + 4];
#pragma unroll
            for (int s2 = 4; s2 > 0; --s2) { cm[s2] = cm[s2 - 1]; cf[s2] = cf[s2 - 1]; }
            cm[0] = ncm; cf[0] = ncf;
        }
        // 2D sums of slice zc-1 (y-phase of iter n-1) -> ring
        if (n >= 1) {
            const int pp = (n - 1) & 1;
            const float* bq = &box[pp][tx][0][ty];    // f-stride 20 dwords -> read2 merge
            const float s0 = bq[0], s1 = bq[20], s2v = bq[40], s3 = bq[60], s4 = bq[80];
#pragma unroll
            for (int s = 0; s < 4; ++s)
#pragma unroll
                for (int f = 0; f < 5; ++f) ring[s][f] = ring[s + 1][f];
            ring[4][0] = s0; ring[4][1] = s1; ring[4][2] = s2v; ring[4][3] = s3; ring[4][4] = s4;
        }

        if (emitv) {
            float sum_m = 0.f, sum_f = 0.f, sum_mm = 0.f, sum_ff = 0.f, sum_mf = 0.f;
#pragma unroll
            for (int s = 0; s < 5; ++s) {
                sum_m  += ring[s][0];
                sum_f  += ring[s][1];
                sum_mm += ring[s][2];
                sum_ff += ring[s][3];
                sum_mf += ring[s][4];
            }
            const int vidx = vbase + (n - 5) * SLICE;
            const int tsl = (n + 1) & 3;       // T slot of slice z (written iter n-3)
            const int cy = ty + 2;
            const float mc = cm[3];            // center at z
            const float fc = cf[3];
            const float Tc = mc + fc;

            // gradient sums via T field: 2 read2-mergeable pairs
            const float* tp = &Tf[tsl][cy][tx + 1];       // {gx-1, gx+1}: offs 0,2
            const float Txm = tp[0], Txp = tp[2];
            const float* tq = &Tf[tsl][cy - 1][tx + 2];   // {gy-1, gy+1}: offs 0,40
            const float Tym = tq[0], Typ = tq[40];

            float gsx, gsy, gsz;
            if (gx == 0)          gsx = Txp - Tc;
            else if (gx == WW-1)  gsx = Tc - Txm;
            else                  gsx = 0.5f * (Txp - Txm);
            if (gy == 0)          gsy = Typ - Tc;
            else if (gy == HH-1)  gsy = Tc - Tym;
            else                  gsy = 0.5f * (Typ - Tym);
            const float Tzm = cm[4] + cf[4], Tzp = cm[2] + cf[2];
            if (z == 0)           gsz = Tzp - Tc;
            else if (z == DD-1)   gsz = Tc - Tzm;
            else                  gsz = 0.5f * (Tzp - Tzm);

            const float u = ((um != 0) || (uf != 0)) ? 1.0f : 0.0f;

            const float npix = 125.0f;
            const float inv_npix = 1.0f / 125.0f;
            const float mean_m = sum_m * inv_npix;
            const float mean_f = sum_f * inv_npix;
            const float var_m = sum_mm - 2.0f * mean_m * sum_m + npix * mean_m * mean_m;
            const float var_f = sum_ff - 2.0f * mean_f * sum_f + npix * mean_f * mean_f;
            const float var_mf = var_m * var_f;
            const float cross = sum_mf - mean_f * sum_m - mean_m * sum_f + npix * mean_m * mean_f;
            const float mmc = mc - mean_m;
            const float fmc = fc - mean_f;
            const bool ok = (var_mf > 1e-5f) && (var_f > 1e-5f) && (fmc != 0.0f) && (mmc != 0.0f);
            float factor = 0.0f;
            if (ok) factor = 2.0f * cross / var_mf * (mmc - cross * fmc / var_f);

            const float nf = -factor * 0.5f * u;
            out[vidx]            = nf * gsz;   // ch 0: d/dD
            out[NVOX + vidx]     = nf * gsy;   // ch 1: d/dH
            out[2 * NVOX + vidx] = nf * gsx;   // ch 2: d/dW
        }

        __syncthreads();   // B: xs/Tf ready; emit/x reads of raw done

        // ---- y-phase: 160 chunk-of-8 sliding tasks -> box[n&1] ----
        if (tid < 160) {
            const int x  = tid & 15;
            const int c8 = ((tid >> 4) & 1) * 8;   // 0 or 8
            const int f  = tid >> 5;               // 0..4
            const float* xp = &xs[f][c8][x];       // stride 20 dwords -> read2 merge
            float v[12];
#pragma unroll
            for (int j = 0; j < 12; ++j) v[j] = xp[20 * j];
            float o[8];
            float s = v[0] + v[1] + v[2] + v[3] + v[4];
            o[0] = s;
#pragma unroll
            for (int j = 1; j < 8; ++j) { s += v[j + 4] - v[j - 1]; o[j] = s; }
            float* bp = &box[n & 1][x][f][c8];
            *(float4*)bp       = make_float4(o[0], o[1], o[2], o[3]);
            *(float4*)(bp + 4) = make_float4(o[4], o[5], o[6], o[7]);
        }
        // no trailing barrier:
        //  - commit(n+1) writes raw after B(n); iter-n raw reads were pre-B.
        //  - next x-phase (writes xs/Tf[(n+1)&3]) is fenced by next barrier A;
        //    Tf[(n+1)&3] was last read at emit(n) before B(n).
        //  - box[n&1] is read at emit(n+1) after A(n+1), rewritten at y(n+2).
    }
}

extern "C" void kernel_launch(void* const* d_in, const int* in_sizes, int n_in,
                              void* d_out, int out_size, void* d_ws, size_t ws_size,
                              hipStream_t stream)
{
    const float* mimg  = (const float*)d_in[0];
    const float* fimg  = (const float*)d_in[1];
    const int*   mmask = (const int*)d_in[2];
    const int*   fmask = (const int*)d_in[3];
    float* out = (float*)d_out;

    dim3 grid(NBLK, 1, 1);   // 2304 blocks
    dim3 block(256, 1, 1);
    hipLaunchKernelGGL(ncc_forces_kernel, grid, block, 0, stream,
                       mimg, fimg, mmask, fmask, out);
}